// Round 8
// baseline (352.538 us; speedup 1.0000x reference)
//
#include <hip/hip_runtime.h>
#include <hip/hip_bf16.h>

typedef unsigned short u16;
typedef short s4v __attribute__((ext_vector_type(4)));
typedef short s8v __attribute__((ext_vector_type(8)));
typedef float f4v __attribute__((ext_vector_type(4)));

#define F 128
#define CIN 1024
#define CMID 512
#define XP 130
#define K9 9216

// gemm LDS element offsets (u16 units)
#define A_ELEMS 8704           // 136 rows * 64
#define B_ELEMS 8192           // 128 rows * 64
#define AOFF(b) ((b) * A_ELEMS)
#define BOFF(b) (2 * A_ELEMS + (b) * B_ELEMS)

__device__ __forceinline__ u16 f2bf(float v) {
    union { float f; unsigned u; } x; x.f = v;
    unsigned r = x.u + 0x7fff + ((x.u >> 16) & 1);
    return (u16)(r >> 16);
}

__device__ __forceinline__ void gl16(const u16* g, u16* l) {
    __builtin_amdgcn_global_load_lds(
        (const __attribute__((address_space(1))) void*)g,
        (__attribute__((address_space(3))) void*)l,
        16, 0, 0);
}

// anchor base sizes: ratios {0.5,1,2} x scales {8,16,32}
__constant__ float WBASE[9] = {184.f, 368.f, 736.f, 128.f, 256.f, 512.f,  88.f, 176.f, 352.f};
__constant__ float HBASE[9] = { 96.f, 192.f, 384.f, 128.f, 256.f, 512.f, 176.f, 352.f, 704.f};

// ---------------- fused prep (round-4 version, at floor) --------------------
__global__ __launch_bounds__(256) void prep_all(
    const float* __restrict__ x, const float* __restrict__ bw,
    const float* __restrict__ cls_w, const float* __restrict__ reg_w,
    u16* __restrict__ xpad, u16* __restrict__ wt, u16* __restrict__ wc,
    unsigned* __restrict__ cnt, int doTail) {
    __shared__ u16 ldsT[64 * 132];     // 16896 B -> high occupancy
    const int b = blockIdx.x;
    const int tid = threadIdx.x;

    if (b < 2048) {                      // ---- x transpose+pad (thin blocks)
        const int h  = b >> 4;
        const int cb = (b & 15) * 64;
        {   // read f32, convert to bf16, packed b64 LDS write ([c][w] layout)
            const int L = tid & 31, cl = tid >> 5;    // w4 lane, c sub-lane
            const int w4 = L * 4;
            #pragma unroll
            for (int p = 0; p < 8; ++p) {
                const int c = p * 8 + cl;
                f4v v = *(const f4v*)&x[(cb + c) * (F * F) + h * F + w4];
                s4v pk;
                #pragma unroll
                for (int k = 0; k < 4; ++k) pk[k] = (short)f2bf(v[k]);
                *(s4v*)&ldsT[c * 132 + w4] = pk;      // byte addr 264c+8L: 8-aligned
            }
        }
        __syncthreads();
        {   // gather 8 consecutive c per lane -> one s8v global store
            const int cs = (tid & 7) * 8;
            const int wb = tid >> 3;                  // 0..31
            #pragma unroll
            for (int p = 0; p < 4; ++p) {
                const int w = p * 32 + wb;
                s8v o;
                #pragma unroll
                for (int j = 0; j < 8; ++j) o[j] = (short)ldsT[(cs + j) * 132 + w];
                *(s8v*)&xpad[((h + 1) * XP + (w + 1)) * CIN + cb + cs] = o;
            }
        }
    } else if (b < 2560) {               // ---- base_w OIHW -> [oc][dydx][c], direct
        const int oc = b - 2048;
        #pragma unroll 1
        for (int p = 0; p < 4; ++p) {
            const int c = p * 256 + tid;
            const float* src = bw + oc * K9 + c * 9;  // 9 consecutive f32 per c
            #pragma unroll
            for (int q = 0; q < 9; ++q)
                wt[oc * K9 + q * 1024 + c] = f2bf(src[q]);   // coalesced u16 stores
        }
    } else if (b < 2818) {               // ---- border zero (vectorized)
        int t = (b - 2560) * 256 + tid;  // 516*128 chunks of 8 u16
        int cell = t >> 7, c8 = (t & 127) * 8;
        int h, w;
        if (cell < 130)      { h = 0;   w = cell; }
        else if (cell < 260) { h = 129; w = cell - 130; }
        else { int rm = cell - 260; h = 1 + (rm >> 1); w = (rm & 1) * 129; }
        s8v z = {};
        *(s8v*)&xpad[(h * XP + w) * CIN + c8] = z;
    } else {                             // ---- combined 1x1 weights (+ cnt zero)
        int t = (b - 2818) * 256 + tid;  // 64*512
        int oc = t >> 9, c = t & 511;
        float v = 0.f;
        if (oc < 18)      v = cls_w[oc * 512 + c];
        else if (oc < 54) v = reg_w[(oc - 18) * 512 + c];
        wc[t] = f2bf(v);
        if (doTail && b == 2818 && tid < 128) cnt[tid] = 0u;   // tail counters
    }
}

// ---------------- stage23 body (shared by tail and fallback kernel) ---------
// Computes 1x1 convs + softmax + proposals for rows [m0, m0+32).
// part must be a [4][32][65] float LDS region. Ends with __syncthreads().
__device__ __forceinline__ void stage23_body(
    const u16* __restrict__ rpn, const u16* __restrict__ wc,
    const float* __restrict__ cls_b, const float* __restrict__ reg_b,
    float* __restrict__ out, float (*part)[32][65], int m0, int tid) {
    const int lane = tid & 63, wv = tid >> 6;
    const int lm = lane & 15, lq = lane >> 4;

    #pragma unroll
    for (int g = 0; g < 2; ++g) {
        f4v acc[4] = {};
        const u16* arow = rpn + (m0 + g * 16 + lm) * CMID + wv * 128 + lq * 8;
        const u16* brow = wc + lm * CMID + wv * 128 + lq * 8;
        #pragma unroll
        for (int k = 0; k < 4; ++k) {
            s8v af = *(const s8v*)(arow + k * 32);
            #pragma unroll
            for (int ni = 0; ni < 4; ++ni) {
                s8v bf = *(const s8v*)(brow + ni * 16 * CMID + k * 32);
                acc[ni] = __builtin_amdgcn_mfma_f32_16x16x32_bf16(af, bf, acc[ni], 0, 0, 0);
            }
        }
        #pragma unroll
        for (int ni = 0; ni < 4; ++ni)
            #pragma unroll
            for (int rr = 0; rr < 4; ++rr)
                part[wv][g * 16 + lq * 4 + rr][ni * 16 + lm] = acc[ni][rr];
    }
    __syncthreads();

    float vsum[8];
    const int col = tid & 63, rb = tid >> 6;
    const float bv = col < 18 ? cls_b[col] : (col < 54 ? reg_b[col - 18] : 0.f);
    #pragma unroll
    for (int rr = 0; rr < 8; ++rr) {
        const int row = rb * 8 + rr;
        vsum[rr] = part[0][row][col] + part[1][row][col]
                 + part[2][row][col] + part[3][row][col] + bv;
    }
    __syncthreads();
    #pragma unroll
    for (int rr = 0; rr < 8; ++rr)
        part[0][rb * 8 + rr][col] = vsum[rr];
    __syncthreads();

    #pragma unroll 1
    for (int g = 0; g < 2; ++g) {
        if (tid < 144) {
            const int pl0 = tid / 9, a = tid - pl0 * 9;
            const int pl = g * 16 + pl0;
            const float* v = part[0][pl];
            const int ch = 2 * a + 1;
            const int pair = (ch < 9) ? ch + 9 : ch - 9;
            const float score = 1.f / (1.f + expf(v[pair] - v[ch]));
            const float r0 = v[18 + 4 * a], r1 = v[19 + 4 * a];
            const float r2 = v[20 + 4 * a], r3 = v[21 + 4 * a];
            const float wb = WBASE[a], hb = HBASE[a];
            const int p = m0 + pl;
            const int h = p >> 7, w = p & 127;
            float* o = out + (p * 9 + a) * 5;
            o[0] = h * 16.f + wb * r0;
            o[1] = w * 16.f + hb * r1;
            o[2] = wb + expf(r2);
            o[3] = hb + expf(r3);
            o[4] = score;
        }
    }
    __syncthreads();   // part reused by next chunk
}

// ---------------- stage 1: implicit-GEMM 3x3 conv + bias + ReLU ------------
// Round-6 structure (top-of-phase counted vmcnt, T1 XCD remap; 134.5 us) +
// counter-elected stage23 TAIL: the 4 same-gh blocks (same XCD under the
// remap -> rpn re-reads are same-L2 hits) atomically count completion; the
// last one runs stage23 for rows [gh*128, gh*128+128). Removes a dispatch;
// stage23 hides under gemm's block-completion stagger.
__global__ __launch_bounds__(256, 2) void gemm_conv(
    const u16* __restrict__ xpad, const u16* __restrict__ wt,
    const float* __restrict__ bias, u16* __restrict__ rpn,
    const u16* __restrict__ wc, const float* __restrict__ cls_b,
    const float* __restrict__ reg_b, float* __restrict__ out,
    unsigned* __restrict__ cnt, int doTail) {
    __shared__ u16 smem[2 * A_ELEMS + 2 * B_ELEMS];   // 67584 B
    __shared__ int tailOld;
    const int tid = threadIdx.x;
    const int w_id = (blockIdx.x & 7) * 64 + (blockIdx.x >> 3);   // XCD remap
    const int oc0 = ((w_id & 7) >> 1) * 128;
    const int gh  = (w_id >> 3) * 2 + (w_id & 1);

    const int lane = tid & 63;
    const int wv = tid >> 6;
    const int lm = lane & 15;
    const int lq = lane >> 4;
    const int wm = (wv >> 1) * 64;
    const int wn = (wv & 1) * 64;

    // source-side XOR swizzle: lane L stages data seg (L&7)^((L>>3)&7) of its row
    const int sw = (lane & 7) ^ ((lane >> 3) & 7);
    const u16* pA = xpad + (lane >> 3) * CIN + sw * 8;
    const u16* pB = wt + (size_t)(oc0 + wv * 32 + (lane >> 3)) * K9 + sw * 8;

    f4v acc[4][4] = {};

    auto issueA = [&](int ms) {
        const int dy = ms >> 4, cc = ms & 15;
        const u16* src = pA + ((gh + dy) * XP) * CIN + cc * 64;
        u16* dst = &smem[AOFF(ms & 1)];
        #pragma unroll
        for (int jj = 0; jj < 4; ++jj) {
            const int ci = wv * 4 + jj;
            gl16(src + ci * 8 * CIN, dst + ci * 512);
        }
        if (wv == 0) gl16(src + 16 * 8 * CIN, dst + 16 * 512);  // rows 128..135
    };
    auto issueB = [&](int ms, int dx, int buf) {
        const int dy = ms >> 4, cc = ms & 15;
        const int dydx = dy * 3 + dx;
        const u16* src = pB + dydx * CIN + cc * 64;
        u16* dst = &smem[BOFF(buf) + wv * 32 * 64];
        #pragma unroll
        for (int jj = 0; jj < 4; ++jj)
            gl16(src + jj * 8 * K9, dst + jj * 8 * 64);
    };

    issueA(0);
    issueB(0, 0, 0);

    for (int ms = 0; ms < 48; ++ms) {
        const u16* Ab = &smem[AOFF(ms & 1)];
        #pragma unroll
        for (int dx = 0; dx < 3; ++dx) {
            const int t = ms * 3 + dx;

            // ---- top-of-phase wait: phase-t staging landed (>=1 phase slack)
            if (dx == 1) {
                if (ms < 47) {
                    if (wv == 0) asm volatile("s_waitcnt vmcnt(5)" ::: "memory");
                    else         asm volatile("s_waitcnt vmcnt(4)" ::: "memory");
                } else {
                    asm volatile("s_waitcnt vmcnt(0)" ::: "memory");
                }
            } else {
                asm volatile("s_waitcnt vmcnt(0)" ::: "memory");
            }
            __builtin_amdgcn_s_barrier();

            // ---- issue staging for phase t+1 (WAR-safe)
            if (t + 1 < 144) {
                const int msn = (dx == 2) ? ms + 1 : ms;
                const int dxn = (dx == 2) ? 0 : dx + 1;
                issueB(msn, dxn, (t + 1) & 1);
            }
            if (dx == 0 && ms + 1 < 48) issueA(ms + 1);

            // ---- compute phase t
            const u16* Bb = &smem[BOFF(t & 1)];
            #pragma unroll
            for (int kk = 0; kk < 2; ++kk) {
                const int kseg = kk * 4 + lq;
                s8v af[4], bfr[4];
                #pragma unroll
                for (int i = 0; i < 4; ++i) {
                    const int ra = wm + i * 16 + lm + dx;
                    const int rb = wn + i * 16 + lm;
                    af[i]  = *(const s8v*)&Ab[ra * 64 + ((kseg ^ (ra & 7)) << 3)];
                    bfr[i] = *(const s8v*)&Bb[rb * 64 + ((kseg ^ (rb & 7)) << 3)];
                }
                #pragma unroll
                for (int mi = 0; mi < 4; ++mi)
                    #pragma unroll
                    for (int ni = 0; ni < 4; ++ni)
                        acc[mi][ni] = __builtin_amdgcn_mfma_f32_16x16x32_bf16(
                            af[mi], bfr[ni], acc[mi][ni], 0, 0, 0);
            }
        }
    }

    #pragma unroll
    for (int ni = 0; ni < 4; ++ni) {
        const int oc = oc0 + wn + ni * 16 + lm;
        const float bv = bias[oc];
        #pragma unroll
        for (int mi = 0; mi < 4; ++mi) {
            #pragma unroll
            for (int rr = 0; rr < 4; ++rr) {
                const int m = wm + mi * 16 + lq * 4 + rr;   // w index
                float v = acc[mi][ni][rr] + bv;
                v = v > 0.f ? v : 0.f;
                rpn[(gh * 128 + m) * CMID + oc] = f2bf(v);
            }
        }
    }

    // ---- counter-elected stage23 tail -------------------------------------
    if (doTail) {
        __threadfence();                 // rpn stores visible device-wide
        __syncthreads();                 // all threads' fences done
        if (tid == 0) tailOld = (int)atomicAdd(&cnt[gh], 1u);
        __syncthreads();
        if (tailOld == 3) {              // last of the 4 oc-quarter blocks
            __threadfence();             // acquire side
            float (*part)[32][65] = (float(*)[32][65])smem;   // 33280 B reuse
            #pragma unroll 1
            for (int g4 = 0; g4 < 4; ++g4)
                stage23_body(rpn, wc, cls_b, reg_b, out, part,
                             gh * 128 + g4 * 32, tid);
        }
    }
}

// ---------------- fallback stage23 kernel (only if ws lacks cnt slack) -----
__global__ __launch_bounds__(256) void stage23(
    const u16* __restrict__ rpn, const u16* __restrict__ wc,
    const float* __restrict__ cls_b, const float* __restrict__ reg_b,
    float* __restrict__ out) {
    __shared__ float part[4][32][65];
    stage23_body(rpn, wc, cls_b, reg_b, out, part, blockIdx.x * 32, threadIdx.x);
}

extern "C" void kernel_launch(void* const* d_in, const int* in_sizes, int n_in,
                              void* d_out, int out_size, void* d_ws, size_t ws_size,
                              hipStream_t stream) {
    const float* x      = (const float*)d_in[0];
    const float* base_w = (const float*)d_in[1];
    const float* base_b = (const float*)d_in[2];
    const float* cls_w  = (const float*)d_in[3];
    const float* cls_b  = (const float*)d_in[4];
    const float* reg_w  = (const float*)d_in[5];
    const float* reg_b  = (const float*)d_in[6];
    float* out = (float*)d_out;

    char* ws = (char*)d_ws;
    u16* xpad = (u16*)ws;                                   // 34,611,200 B
    u16* wt   = (u16*)(ws + 34611200);                      //  9,437,184 B
    u16* wc   = (u16*)(ws + 34611200 + 9437184);            //     65,536 B
    u16* rpn  = (u16*)(ws + 34611200 + 9437184 + 65536);    // 16,777,216 B
    const size_t base = 34611200 + 9437184 + 65536 + 16777216;  // 60,891,136
    const int doTail = (ws_size >= base + 512) ? 1 : 0;
    unsigned* cnt = (unsigned*)(ws + base);                 //        512 B

    prep_all<<<2946, 256, 0, stream>>>(x, base_w, cls_w, reg_w, xpad, wt, wc,
                                       cnt, doTail);
    gemm_conv<<<512, 256, 0, stream>>>(xpad, wt, base_b, rpn, wc, cls_b,
                                       reg_b, out, cnt, doTail);
    if (!doTail)
        stage23<<<512, 256, 0, stream>>>(rpn, wc, cls_b, reg_b, out);
}

// Round 9
// 259.562 us; speedup vs baseline: 1.3582x; 1.3582x over previous
//
#include <hip/hip_runtime.h>
#include <hip/hip_bf16.h>

typedef unsigned short u16;
typedef short s4v __attribute__((ext_vector_type(4)));
typedef short s8v __attribute__((ext_vector_type(8)));
typedef float f4v __attribute__((ext_vector_type(4)));

#define F 128
#define CIN 1024
#define CMID 512
#define XP 130
#define K9 9216

// gemm LDS element offsets (u16 units)
#define A_ELEMS 8704           // 136 rows * 64
#define B_ELEMS 8192           // 128 rows * 64
#define AOFF(b) ((b) * A_ELEMS)
#define BOFF(b) (2 * A_ELEMS + (b) * B_ELEMS)

__device__ __forceinline__ u16 f2bf(float v) {
    union { float f; unsigned u; } x; x.f = v;
    unsigned r = x.u + 0x7fff + ((x.u >> 16) & 1);
    return (u16)(r >> 16);
}

__device__ __forceinline__ void gl16(const u16* g, u16* l) {
    __builtin_amdgcn_global_load_lds(
        (const __attribute__((address_space(1))) void*)g,
        (__attribute__((address_space(3))) void*)l,
        16, 0, 0);
}

// anchor base sizes: ratios {0.5,1,2} x scales {8,16,32}
__constant__ float WBASE[9] = {184.f, 368.f, 736.f, 128.f, 256.f, 512.f,  88.f, 176.f, 352.f};
__constant__ float HBASE[9] = { 96.f, 192.f, 384.f, 128.f, 256.f, 512.f, 176.f, 352.f, 704.f};

// ---------------- fused prep (round-4 version, at floor) --------------------
__global__ __launch_bounds__(256) void prep_all(
    const float* __restrict__ x, const float* __restrict__ bw,
    const float* __restrict__ cls_w, const float* __restrict__ reg_w,
    u16* __restrict__ xpad, u16* __restrict__ wt, u16* __restrict__ wc) {
    __shared__ u16 ldsT[64 * 132];     // 16896 B -> high occupancy
    const int b = blockIdx.x;
    const int tid = threadIdx.x;

    if (b < 2048) {                      // ---- x transpose+pad (thin blocks)
        const int h  = b >> 4;
        const int cb = (b & 15) * 64;
        {   // read f32, convert to bf16, packed b64 LDS write ([c][w] layout)
            const int L = tid & 31, cl = tid >> 5;    // w4 lane, c sub-lane
            const int w4 = L * 4;
            #pragma unroll
            for (int p = 0; p < 8; ++p) {
                const int c = p * 8 + cl;
                f4v v = *(const f4v*)&x[(cb + c) * (F * F) + h * F + w4];
                s4v pk;
                #pragma unroll
                for (int k = 0; k < 4; ++k) pk[k] = (short)f2bf(v[k]);
                *(s4v*)&ldsT[c * 132 + w4] = pk;      // byte addr 264c+8L: 8-aligned
            }
        }
        __syncthreads();
        {   // gather 8 consecutive c per lane -> one s8v global store
            const int cs = (tid & 7) * 8;
            const int wb = tid >> 3;                  // 0..31
            #pragma unroll
            for (int p = 0; p < 4; ++p) {
                const int w = p * 32 + wb;
                s8v o;
                #pragma unroll
                for (int j = 0; j < 8; ++j) o[j] = (short)ldsT[(cs + j) * 132 + w];
                *(s8v*)&xpad[((h + 1) * XP + (w + 1)) * CIN + cb + cs] = o;
            }
        }
    } else if (b < 2560) {               // ---- base_w OIHW -> [oc][dydx][c], direct
        const int oc = b - 2048;
        #pragma unroll 1
        for (int p = 0; p < 4; ++p) {
            const int c = p * 256 + tid;
            const float* src = bw + oc * K9 + c * 9;  // 9 consecutive f32 per c
            #pragma unroll
            for (int q = 0; q < 9; ++q)
                wt[oc * K9 + q * 1024 + c] = f2bf(src[q]);   // coalesced u16 stores
        }
    } else if (b < 2818) {               // ---- border zero (vectorized)
        int t = (b - 2560) * 256 + tid;  // 516*128 chunks of 8 u16
        int cell = t >> 7, c8 = (t & 127) * 8;
        int h, w;
        if (cell < 130)      { h = 0;   w = cell; }
        else if (cell < 260) { h = 129; w = cell - 130; }
        else { int rm = cell - 260; h = 1 + (rm >> 1); w = (rm & 1) * 129; }
        s8v z = {};
        *(s8v*)&xpad[(h * XP + w) * CIN + c8] = z;
    } else {                             // ---- combined 1x1 weights
        int t = (b - 2818) * 256 + tid;  // 64*512
        int oc = t >> 9, c = t & 511;
        float v = 0.f;
        if (oc < 18)      v = cls_w[oc * 512 + c];
        else if (oc < 54) v = reg_w[(oc - 18) * 512 + c];
        wc[t] = f2bf(v);
    }
}

// ---------------- stage 1: implicit-GEMM 3x3 conv + bias + ReLU ------------
// R7 geometry (64x64 waves, 256 thr, 2 blocks/CU) + T1 XCD remap, with the
// phase wait moved to the TOP of each phase: vmcnt(counted) + raw s_barrier,
// staging issued AFTER the barrier. Every wait targets loads issued >=1
// full phase earlier (~2300 cyc slack vs ~900 cyc HBM); dx1 relaxes to
// vmcnt(4/5). 144 barriers total; no second barrier; dx fully unrolled.
// WAR safety: buf (t+1)&1 last ds_read in phase t-1; those reads retire
// before each wave's MFMAs, hence before it reaches this barrier.
// Measured (round 6): 134.5 us, MfmaUtil 52, FETCH 110 MB, 0 conflicts.
__global__ __launch_bounds__(256, 2) void gemm_conv(
    const u16* __restrict__ xpad, const u16* __restrict__ wt,
    const float* __restrict__ bias, u16* __restrict__ rpn) {
    __shared__ u16 smem[2 * A_ELEMS + 2 * B_ELEMS];   // 67584 B
    const int tid = threadIdx.x;
    const int w_id = (blockIdx.x & 7) * 64 + (blockIdx.x >> 3);   // XCD remap
    const int oc0 = ((w_id & 7) >> 1) * 128;
    const int gh  = (w_id >> 3) * 2 + (w_id & 1);

    const int lane = tid & 63;
    const int wv = tid >> 6;
    const int lm = lane & 15;
    const int lq = lane >> 4;
    const int wm = (wv >> 1) * 64;
    const int wn = (wv & 1) * 64;

    // source-side XOR swizzle: lane L stages data seg (L&7)^((L>>3)&7) of its row
    const int sw = (lane & 7) ^ ((lane >> 3) & 7);
    const u16* pA = xpad + (lane >> 3) * CIN + sw * 8;
    const u16* pB = wt + (size_t)(oc0 + wv * 32 + (lane >> 3)) * K9 + sw * 8;

    f4v acc[4][4] = {};

    auto issueA = [&](int ms) {
        const int dy = ms >> 4, cc = ms & 15;
        const u16* src = pA + ((gh + dy) * XP) * CIN + cc * 64;
        u16* dst = &smem[AOFF(ms & 1)];
        #pragma unroll
        for (int jj = 0; jj < 4; ++jj) {
            const int ci = wv * 4 + jj;
            gl16(src + ci * 8 * CIN, dst + ci * 512);
        }
        if (wv == 0) gl16(src + 16 * 8 * CIN, dst + 16 * 512);  // rows 128..135
    };
    auto issueB = [&](int ms, int dx, int buf) {
        const int dy = ms >> 4, cc = ms & 15;
        const int dydx = dy * 3 + dx;
        const u16* src = pB + dydx * CIN + cc * 64;
        u16* dst = &smem[BOFF(buf) + wv * 32 * 64];
        #pragma unroll
        for (int jj = 0; jj < 4; ++jj)
            gl16(src + jj * 8 * K9, dst + jj * 8 * 64);
    };

    issueA(0);
    issueB(0, 0, 0);

    for (int ms = 0; ms < 48; ++ms) {
        const u16* Ab = &smem[AOFF(ms & 1)];
        #pragma unroll
        for (int dx = 0; dx < 3; ++dx) {
            const int t = ms * 3 + dx;

            // ---- top-of-phase wait: phase-t staging landed.
            // dx1: only loads newer than B(t) are this ms's A(ms+1) issues.
            if (dx == 1) {
                if (ms < 47) {
                    if (wv == 0) asm volatile("s_waitcnt vmcnt(5)" ::: "memory");
                    else         asm volatile("s_waitcnt vmcnt(4)" ::: "memory");
                } else {
                    asm volatile("s_waitcnt vmcnt(0)" ::: "memory");
                }
            } else {
                // B(t) is the newest outstanding load (issued last phase):
                // vmcnt(0), but with >=1 phase (~2300 cyc) of slack.
                asm volatile("s_waitcnt vmcnt(0)" ::: "memory");
            }
            __builtin_amdgcn_s_barrier();

            // ---- issue staging for phase t+1 (WAR-safe, see header comment)
            if (t + 1 < 144) {
                const int msn = (dx == 2) ? ms + 1 : ms;
                const int dxn = (dx == 2) ? 0 : dx + 1;
                issueB(msn, dxn, (t + 1) & 1);
            }
            if (dx == 0 && ms + 1 < 48) issueA(ms + 1);

            // ---- compute phase t
            const u16* Bb = &smem[BOFF(t & 1)];
            #pragma unroll
            for (int kk = 0; kk < 2; ++kk) {
                const int kseg = kk * 4 + lq;
                s8v af[4], bfr[4];
                #pragma unroll
                for (int i = 0; i < 4; ++i) {
                    const int ra = wm + i * 16 + lm + dx;
                    const int rb = wn + i * 16 + lm;
                    af[i]  = *(const s8v*)&Ab[ra * 64 + ((kseg ^ (ra & 7)) << 3)];
                    bfr[i] = *(const s8v*)&Bb[rb * 64 + ((kseg ^ (rb & 7)) << 3)];
                }
                #pragma unroll
                for (int mi = 0; mi < 4; ++mi)
                    #pragma unroll
                    for (int ni = 0; ni < 4; ++ni)
                        acc[mi][ni] = __builtin_amdgcn_mfma_f32_16x16x32_bf16(
                            af[mi], bfr[ni], acc[mi][ni], 0, 0, 0);
            }
            // no bottom-of-phase barrier
        }
    }

    #pragma unroll
    for (int ni = 0; ni < 4; ++ni) {
        const int oc = oc0 + wn + ni * 16 + lm;
        const float bv = bias[oc];
        #pragma unroll
        for (int mi = 0; mi < 4; ++mi) {
            #pragma unroll
            for (int rr = 0; rr < 4; ++rr) {
                const int m = wm + mi * 16 + lq * 4 + rr;   // w index
                float v = acc[mi][ni][rr] + bv;
                v = v > 0.f ? v : 0.f;
                rpn[(gh * 128 + m) * CMID + oc] = f2bf(v);
            }
        }
    }
}

// ---------------- stage 2+3: 1x1 convs (MFMA, K-split) + softmax + proposals
// (round-4 version) 512 blocks x 32 rows; 4 waves K-split; LDS reduce.
__global__ __launch_bounds__(256) void stage23(
    const u16* __restrict__ rpn, const u16* __restrict__ wc,
    const float* __restrict__ cls_b, const float* __restrict__ reg_b,
    float* __restrict__ out) {
    __shared__ float part[4][32][65];
    const int tid = threadIdx.x, lane = tid & 63, wv = tid >> 6;
    const int lm = lane & 15, lq = lane >> 4;
    const int m0 = blockIdx.x * 32;

    #pragma unroll
    for (int g = 0; g < 2; ++g) {
        f4v acc[4] = {};
        const u16* arow = rpn + (m0 + g * 16 + lm) * CMID + wv * 128 + lq * 8;
        const u16* brow = wc + lm * CMID + wv * 128 + lq * 8;
        #pragma unroll
        for (int k = 0; k < 4; ++k) {
            s8v af = *(const s8v*)(arow + k * 32);
            #pragma unroll
            for (int ni = 0; ni < 4; ++ni) {
                s8v bf = *(const s8v*)(brow + ni * 16 * CMID + k * 32);
                acc[ni] = __builtin_amdgcn_mfma_f32_16x16x32_bf16(af, bf, acc[ni], 0, 0, 0);
            }
        }
        #pragma unroll
        for (int ni = 0; ni < 4; ++ni)
            #pragma unroll
            for (int rr = 0; rr < 4; ++rr)
                part[wv][g * 16 + lq * 4 + rr][ni * 16 + lm] = acc[ni][rr];
    }
    __syncthreads();

    float vsum[8];
    const int col = tid & 63, rb = tid >> 6;
    const float bv = col < 18 ? cls_b[col] : (col < 54 ? reg_b[col - 18] : 0.f);
    #pragma unroll
    for (int rr = 0; rr < 8; ++rr) {
        const int row = rb * 8 + rr;
        vsum[rr] = part[0][row][col] + part[1][row][col]
                 + part[2][row][col] + part[3][row][col] + bv;
    }
    __syncthreads();
    #pragma unroll
    for (int rr = 0; rr < 8; ++rr)
        part[0][rb * 8 + rr][col] = vsum[rr];
    __syncthreads();

    #pragma unroll 1
    for (int g = 0; g < 2; ++g) {
        if (tid < 144) {
            const int pl0 = tid / 9, a = tid - pl0 * 9;
            const int pl = g * 16 + pl0;
            const float* v = part[0][pl];
            const int ch = 2 * a + 1;
            const int pair = (ch < 9) ? ch + 9 : ch - 9;
            const float score = 1.f / (1.f + expf(v[pair] - v[ch]));
            const float r0 = v[18 + 4 * a], r1 = v[19 + 4 * a];
            const float r2 = v[20 + 4 * a], r3 = v[21 + 4 * a];
            const float wb = WBASE[a], hb = HBASE[a];
            const int p = m0 + pl;
            const int h = p >> 7, w = p & 127;
            float* o = out + (p * 9 + a) * 5;
            o[0] = h * 16.f + wb * r0;
            o[1] = w * 16.f + hb * r1;
            o[2] = wb + expf(r2);
            o[3] = hb + expf(r3);
            o[4] = score;
        }
    }
}

extern "C" void kernel_launch(void* const* d_in, const int* in_sizes, int n_in,
                              void* d_out, int out_size, void* d_ws, size_t ws_size,
                              hipStream_t stream) {
    const float* x      = (const float*)d_in[0];
    const float* base_w = (const float*)d_in[1];
    const float* base_b = (const float*)d_in[2];
    const float* cls_w  = (const float*)d_in[3];
    const float* cls_b  = (const float*)d_in[4];
    const float* reg_w  = (const float*)d_in[5];
    const float* reg_b  = (const float*)d_in[6];
    float* out = (float*)d_out;

    char* ws = (char*)d_ws;
    u16* xpad = (u16*)ws;                                   // 34,611,200 B
    u16* wt   = (u16*)(ws + 34611200);                      //  9,437,184 B
    u16* wc   = (u16*)(ws + 34611200 + 9437184);            //     65,536 B
    u16* rpn  = (u16*)(ws + 34611200 + 9437184 + 65536);    // 16,777,216 B

    prep_all<<<2946, 256, 0, stream>>>(x, base_w, cls_w, reg_w, xpad, wt, wc);
    gemm_conv<<<512, 256, 0, stream>>>(xpad, wt, base_b, rpn);
    stage23<<<512, 256, 0, stream>>>(rpn, wc, cls_b, reg_b, out);
}